// Round 1
// baseline (14170.761 us; speedup 1.0000x reference)
//
#include <hip/hip_runtime.h>
#include <hip/hip_bf16.h>

// GRU, T=512 B=64 D=512 H=1024.
// Round 1: per-step kernel-pair baseline. Stream ordering = inter-phase sync.
// bf16 MFMA (16x16x32) GEMM core, fp32 accumulate, fp32 hidden-state master.

typedef __attribute__((ext_vector_type(8))) short bf16x8;
typedef __attribute__((ext_vector_type(4))) float f32x4;

static __device__ __forceinline__ float sigmoidf_fast(float x) {
    return 1.0f / (1.0f + __expf(-x));
}

__global__ __launch_bounds__(256) void k_convert_weights(
    const float* __restrict__ Wz, const float* __restrict__ Wr,
    const float* __restrict__ Wc,
    __hip_bfloat16* __restrict__ Wzr, __hip_bfloat16* __restrict__ Wcb)
{
    const long long NW = 1024LL * 1536LL;
    const long long stride = (long long)gridDim.x * blockDim.x;
    for (long long i = (long long)blockIdx.x * blockDim.x + threadIdx.x;
         i < 3 * NW; i += stride) {
        if (i < NW)            Wzr[i] = __float2bfloat16(Wz[i]);
        else if (i < 2 * NW)   Wzr[i] = __float2bfloat16(Wr[i - NW]);
        else                   Wcb[i - 2 * NW] = __float2bfloat16(Wc[i - 2 * NW]);
    }
}

__global__ __launch_bounds__(256) void k_convert_x(
    const float* __restrict__ x, __hip_bfloat16* __restrict__ xb)
{
    const long long N = 512LL * 64LL * 512LL;
    const long long stride = (long long)gridDim.x * blockDim.x;
    for (long long i = (long long)blockIdx.x * blockDim.x + threadIdx.x;
         i < N; i += stride)
        xb[i] = __float2bfloat16(x[i]);
}

__global__ __launch_bounds__(256) void k_init_h(
    const float* __restrict__ h0, float* __restrict__ hf,
    __hip_bfloat16* __restrict__ hb)
{
    int i = blockIdx.x * blockDim.x + threadIdx.x;  // grid covers 64*1024
    float v = h0[i];
    hf[i] = v;
    hb[i] = __float2bfloat16(v);
}

// Phase 1: z,r = sigmoid([x_t | h] @ Wzr^T + b). Grid: 128 WGs x 256 thr.
// WG j -> 16 output cols of the 2048-wide fused z|r output; wave w -> 16 batch rows.
__global__ __launch_bounds__(256) void k_gates(
    const __hip_bfloat16* __restrict__ xt,   // [64][512]
    const __hip_bfloat16* __restrict__ hb,   // [64][1024] bf16 publish of h
    const float* __restrict__ hf,            // [64][1024] fp32 master of h
    const __hip_bfloat16* __restrict__ Wzr,  // [2048][1536] rows: Wz then Wr
    const float* __restrict__ bz, const float* __restrict__ br,
    float* __restrict__ zf,                  // [64][1024] z gate fp32
    __hip_bfloat16* __restrict__ sb)         // [64][1024] s = r*h bf16
{
    const int lane = threadIdx.x & 63;
    const int wave = threadIdx.x >> 6;
    const int m0 = wave << 4;                 // batch tile base
    const int n0 = blockIdx.x << 4;           // out-col tile base
    const int r15 = lane & 15;
    const int kk = (lane >> 4) << 3;          // per-lane K offset (8 elems)

    const short* Ax = (const short*)xt + (m0 + r15) * 512 + kk;
    const short* Ah = (const short*)hb + (m0 + r15) * 1024 + kk;
    const short* Bw = (const short*)Wzr + (long long)(n0 + r15) * 1536 + kk;

    f32x4 acc = {0.f, 0.f, 0.f, 0.f};
#pragma unroll 8
    for (int ki = 0; ki < 16; ++ki) {         // K = 0..511 (x part)
        bf16x8 a = *(const bf16x8*)(Ax + ki * 32);
        bf16x8 w = *(const bf16x8*)(Bw + ki * 32);
        acc = __builtin_amdgcn_mfma_f32_16x16x32_bf16(a, w, acc, 0, 0, 0);
    }
    const short* Bw2 = Bw + 512;
#pragma unroll 8
    for (int ki = 0; ki < 32; ++ki) {         // K = 512..1535 (h part)
        bf16x8 a = *(const bf16x8*)(Ah + ki * 32);
        bf16x8 w = *(const bf16x8*)(Bw2 + ki * 32);
        acc = __builtin_amdgcn_mfma_f32_16x16x32_bf16(a, w, acc, 0, 0, 0);
    }

    // D layout: col = lane&15, row = (lane>>4)*4 + v  [measured m89]
    const int nc = n0 + r15;
    const int mbase = m0 + ((lane >> 4) << 2);
    if (nc < 1024) {                          // z gate (WG uniform: 1024 % 16 == 0)
        const float bzv = bz[nc];
#pragma unroll
        for (int v = 0; v < 4; ++v) {
            int bm = mbase + v;
            zf[bm * 1024 + nc] = sigmoidf_fast(acc[v] + bzv);
        }
    } else {                                  // r gate -> publish s = r*h
        const int nr = nc - 1024;
        const float brv = br[nr];
#pragma unroll
        for (int v = 0; v < 4; ++v) {
            int bm = mbase + v;
            float rg = sigmoidf_fast(acc[v] + brv);
            sb[bm * 1024 + nr] = __float2bfloat16(rg * hf[bm * 1024 + nr]);
        }
    }
}

// Phase 2: c = tanh([x_t | r*h] @ Wc^T + bc); h' = (1-z)h + z*c. Grid: 64 WGs.
__global__ __launch_bounds__(256) void k_cand(
    const __hip_bfloat16* __restrict__ xt,   // [64][512]
    const __hip_bfloat16* __restrict__ sb,   // [64][1024]
    const __hip_bfloat16* __restrict__ Wcb,  // [1024][1536]
    const float* __restrict__ bc,
    const float* __restrict__ zf,            // [64][1024]
    float* __restrict__ hf,
    __hip_bfloat16* __restrict__ hb,
    float* __restrict__ outt)                // d_out + t*64*1024
{
    const int lane = threadIdx.x & 63;
    const int wave = threadIdx.x >> 6;
    const int m0 = wave << 4;
    const int n0 = blockIdx.x << 4;
    const int r15 = lane & 15;
    const int kk = (lane >> 4) << 3;

    const short* Ax = (const short*)xt + (m0 + r15) * 512 + kk;
    const short* As = (const short*)sb + (m0 + r15) * 1024 + kk;
    const short* Bw = (const short*)Wcb + (long long)(n0 + r15) * 1536 + kk;

    f32x4 acc = {0.f, 0.f, 0.f, 0.f};
#pragma unroll 8
    for (int ki = 0; ki < 16; ++ki) {         // K = 0..511 (x part)
        bf16x8 a = *(const bf16x8*)(Ax + ki * 32);
        bf16x8 w = *(const bf16x8*)(Bw + ki * 32);
        acc = __builtin_amdgcn_mfma_f32_16x16x32_bf16(a, w, acc, 0, 0, 0);
    }
    const short* Bw2 = Bw + 512;
#pragma unroll 8
    for (int ki = 0; ki < 32; ++ki) {         // K = 512..1535 (s = r*h part)
        bf16x8 a = *(const bf16x8*)(As + ki * 32);
        bf16x8 w = *(const bf16x8*)(Bw2 + ki * 32);
        acc = __builtin_amdgcn_mfma_f32_16x16x32_bf16(a, w, acc, 0, 0, 0);
    }

    const int nc = n0 + r15;
    const float bcv = bc[nc];
    const int mbase = m0 + ((lane >> 4) << 2);
#pragma unroll
    for (int v = 0; v < 4; ++v) {
        int bm = mbase + v;
        float c = tanhf(acc[v] + bcv);
        float z = zf[bm * 1024 + nc];
        float h_old = hf[bm * 1024 + nc];
        float h_new = (1.0f - z) * h_old + z * c;
        outt[bm * 1024 + nc] = h_new;
        hf[bm * 1024 + nc] = h_new;
        hb[bm * 1024 + nc] = __float2bfloat16(h_new);
    }
}

extern "C" void kernel_launch(void* const* d_in, const int* in_sizes, int n_in,
                              void* d_out, int out_size, void* d_ws, size_t ws_size,
                              hipStream_t stream)
{
    (void)in_sizes; (void)n_in; (void)out_size; (void)ws_size;
    const float* x  = (const float*)d_in[0];
    const float* h0 = (const float*)d_in[1];
    const float* Wz = (const float*)d_in[2];
    const float* bz = (const float*)d_in[3];
    const float* Wr = (const float*)d_in[4];
    const float* br = (const float*)d_in[5];
    const float* Wc = (const float*)d_in[6];
    const float* bc = (const float*)d_in[7];
    float* out = (float*)d_out;

    // ws layout (bytes, all 256-aligned): total ~43.8 MB
    char* ws = (char*)d_ws;
    __hip_bfloat16* Wzr = (__hip_bfloat16*)(ws);              // [2048][1536] bf16
    __hip_bfloat16* Wcb = (__hip_bfloat16*)(ws + 6291456);    // [1024][1536] bf16
    __hip_bfloat16* xb  = (__hip_bfloat16*)(ws + 9437184);    // [512][64][512] bf16
    float*          hf  = (float*)(ws + 42991616);            // [64][1024] f32
    __hip_bfloat16* hb  = (__hip_bfloat16*)(ws + 43253760);   // [64][1024] bf16
    __hip_bfloat16* sb  = (__hip_bfloat16*)(ws + 43384832);   // [64][1024] bf16
    float*          zf  = (float*)(ws + 43515904);            // [64][1024] f32

    k_convert_weights<<<1024, 256, 0, stream>>>(Wz, Wr, Wc, Wzr, Wcb);
    k_convert_x<<<2048, 256, 0, stream>>>(x, xb);
    k_init_h<<<256, 256, 0, stream>>>(h0, hf, hb);

    for (int t = 0; t < 512; ++t) {
        const __hip_bfloat16* xt = xb + (long long)t * 64 * 512;
        k_gates<<<128, 256, 0, stream>>>(xt, hb, hf, Wzr, bz, br, zf, sb);
        k_cand<<<64, 256, 0, stream>>>(xt, sb, Wcb, bc, zf, hf, hb,
                                       out + (long long)t * 64 * 1024);
    }
}

// Round 3
// 10449.372 us; speedup vs baseline: 1.3561x; 1.3561x over previous
//
#include <hip/hip_runtime.h>
#include <hip/hip_bf16.h>

// GRU, T=512 B=64 D=512 H=1024.
// Round 3: single persistent kernel, weights LDS-resident, manual grid barrier.
// (Round 2 + compile fix: __builtin_amdgcn_fence instead of __hip_atomic_fence.)
// bf16 MFMA (16x16x32), fp32 accumulate, fp32 hidden-state master.

typedef __attribute__((ext_vector_type(8))) short bf16x8;
typedef __attribute__((ext_vector_type(4))) float f32x4;

#define NWG 128
#define TSTEPS 512

static __device__ __forceinline__ float sigmoidf_fast(float x) {
    return 1.0f / (1.0f + __expf(-x));
}

__global__ __launch_bounds__(256) void k_convert_weights(
    const float* __restrict__ Wz, const float* __restrict__ Wr,
    const float* __restrict__ Wc,
    __hip_bfloat16* __restrict__ Wzr, __hip_bfloat16* __restrict__ Wcb)
{
    const long long NW = 1024LL * 1536LL;
    const long long stride = (long long)gridDim.x * blockDim.x;
    for (long long i = (long long)blockIdx.x * blockDim.x + threadIdx.x;
         i < 3 * NW; i += stride) {
        if (i < NW)            Wzr[i] = __float2bfloat16(Wz[i]);
        else if (i < 2 * NW)   Wzr[i] = __float2bfloat16(Wr[i - NW]);
        else                   Wcb[i - 2 * NW] = __float2bfloat16(Wc[i - 2 * NW]);
    }
}

__global__ __launch_bounds__(256) void k_convert_x(
    const float* __restrict__ x, __hip_bfloat16* __restrict__ xb)
{
    const long long N = 512LL * 64LL * 512LL;
    const long long stride = (long long)gridDim.x * blockDim.x;
    for (long long i = (long long)blockIdx.x * blockDim.x + threadIdx.x;
         i < N; i += stride)
        xb[i] = __float2bfloat16(x[i]);
}

__global__ __launch_bounds__(256) void k_init_h(
    const float* __restrict__ h0, float* __restrict__ hf,
    __hip_bfloat16* __restrict__ hb)
{
    int i = blockIdx.x * blockDim.x + threadIdx.x;  // grid covers 64*1024
    float v = h0[i];
    hf[i] = v;
    hb[i] = __float2bfloat16(v);
}

// Distributed-store / master-poll grid barrier. flags[g*16] and go[0] are
// zeroed by hipMemsetAsync before launch; gen is monotone 1..2*TSTEPS.
// Agent-scope fences handle cross-XCD L2 non-coherence.
static __device__ __forceinline__ void grid_barrier(
    unsigned int* flags, unsigned int* go, int g, unsigned int gen)
{
    __syncthreads();  // all WG lanes reached the barrier
    if (g == 0) {
        if (threadIdx.x > 0 && threadIdx.x < NWG) {
            unsigned int* f = flags + threadIdx.x * 16;
            while (__hip_atomic_load(f, __ATOMIC_RELAXED,
                                     __HIP_MEMORY_SCOPE_AGENT) < gen)
                __builtin_amdgcn_s_sleep(1);
        }
        __syncthreads();
        if (threadIdx.x == 0) {
            __builtin_amdgcn_fence(__ATOMIC_RELEASE, "agent");
            __hip_atomic_store(go, gen, __ATOMIC_RELAXED,
                               __HIP_MEMORY_SCOPE_AGENT);
        }
    } else {
        if (threadIdx.x == 0) {
            __builtin_amdgcn_fence(__ATOMIC_RELEASE, "agent");
            __hip_atomic_store(flags + g * 16, gen, __ATOMIC_RELAXED,
                               __HIP_MEMORY_SCOPE_AGENT);
            while (__hip_atomic_load(go, __ATOMIC_RELAXED,
                                     __HIP_MEMORY_SCOPE_AGENT) < gen)
                __builtin_amdgcn_s_sleep(1);
        }
    }
    if (threadIdx.x == 0)
        __builtin_amdgcn_fence(__ATOMIC_ACQUIRE, "agent");
    __syncthreads();
}

// Persistent GRU kernel: 128 WGs x 256 threads, 1 WG/CU (96KB LDS).
// Phase 1: WG g owns fused z|r cols [16g,16g+16); wave w owns batch [16w,16w+16).
// Phase 2: WG g owns cand cols [16*(g>>1),+16), batch half (g&1); waves 0,1 compute.
__global__ __launch_bounds__(256) void k_gru_persistent(
    const __hip_bfloat16* __restrict__ xb,   // [512][64][512]
    float* __restrict__ hf,                  // [64][1024] fp32 master
    __hip_bfloat16* __restrict__ hb,         // [64][1024] bf16 publish
    const __hip_bfloat16* __restrict__ Wzr,  // [2048][1536]
    const __hip_bfloat16* __restrict__ Wcb,  // [1024][1536]
    const float* __restrict__ bz, const float* __restrict__ br,
    const float* __restrict__ bc,
    float* __restrict__ zf,                  // [64][1024]
    __hip_bfloat16* __restrict__ sb,         // [64][1024]
    float* __restrict__ out,                 // [512][64][1024]
    unsigned int* __restrict__ sync)         // flags[128*16] ++ go
{
    __shared__ short w1[16 * 1536];  // 48KB, swizzled, phase-1 weight slice
    __shared__ short w2[16 * 1536];  // 48KB, swizzled, phase-2 weight slice

    const int g = blockIdx.x;
    const int lane = threadIdx.x & 63;
    const int wave = threadIdx.x >> 6;
    const int r15 = lane & 15;
    const int q = lane >> 4;        // 0..3
    const int kk = q << 3;          // per-lane K offset (8 elems)
    const int sw = r15 & 7;         // read-side LDS swizzle

    unsigned int* flags = sync;
    unsigned int* go = sync + NWG * 16;

    // ---- stage weight slices into LDS (once), 16B chunks, blk^(row&7) swizzle
    for (int c = threadIdx.x; c < 16 * 192; c += 256) {
        int row = c / 192, blk = c % 192;
        bf16x8 v = *(const bf16x8*)((const short*)Wzr +
                                    (long long)(g * 16 + row) * 1536 + blk * 8);
        *(bf16x8*)(w1 + (row * 192 + (blk ^ (row & 7))) * 8) = v;
    }
    for (int c = threadIdx.x; c < 16 * 192; c += 256) {
        int row = c / 192, blk = c % 192;
        bf16x8 v = *(const bf16x8*)((const short*)Wcb +
                                    (long long)((g >> 1) * 16 + row) * 1536 + blk * 8);
        *(bf16x8*)(w2 + (row * 192 + (blk ^ (row & 7))) * 8) = v;
    }
    __syncthreads();

    // ---- per-lane constants (fixed across steps)
    const int m0 = wave << 4;                   // phase-1 batch base
    const int nc1 = g * 16 + r15;               // phase-1 fused out col
    const float bias1 = (g < 64) ? bz[nc1] : br[nc1 - 1024];
    const int c0 = (g >> 1) * 16;               // phase-2 out col base
    const int nc2 = c0 + r15;
    const float bias2 = bc[nc2];
    const int mb2 = (g & 1) * 32 + wave * 16;   // phase-2 batch base (waves 0,1)
    const int mbase1 = m0 + (q << 2);
    const int mbase2 = mb2 + (q << 2);

    unsigned int gen = 0;

    for (int t = 0; t < TSTEPS; ++t) {
        const short* xt = (const short*)xb + (long long)t * 64 * 512;

        // ================= Phase 1: z,r gates =================
        {
            const short* Ax = xt + (m0 + r15) * 512 + kk;
            const short* Ah = (const short*)hb + (m0 + r15) * 1024 + kk;
            f32x4 acc = {0.f, 0.f, 0.f, 0.f};
#pragma unroll 8
            for (int ki = 0; ki < 16; ++ki) {
                bf16x8 a = *(const bf16x8*)(Ax + ki * 32);
                bf16x8 w = *(const bf16x8*)(w1 + (r15 * 192 + ((ki * 4 + q) ^ sw)) * 8);
                acc = __builtin_amdgcn_mfma_f32_16x16x32_bf16(a, w, acc, 0, 0, 0);
            }
#pragma unroll 8
            for (int ki = 16; ki < 48; ++ki) {
                bf16x8 a = *(const bf16x8*)(Ah + (ki - 16) * 32);
                bf16x8 w = *(const bf16x8*)(w1 + (r15 * 192 + ((ki * 4 + q) ^ sw)) * 8);
                acc = __builtin_amdgcn_mfma_f32_16x16x32_bf16(a, w, acc, 0, 0, 0);
            }
            if (g < 64) {  // z gate
#pragma unroll
                for (int v = 0; v < 4; ++v) {
                    int bm = mbase1 + v;
                    zf[bm * 1024 + nc1] = sigmoidf_fast(acc[v] + bias1);
                }
            } else {       // r gate -> s = r*h (bf16)
                const int nr = nc1 - 1024;
#pragma unroll
                for (int v = 0; v < 4; ++v) {
                    int bm = mbase1 + v;
                    float rg = sigmoidf_fast(acc[v] + bias1);
                    sb[bm * 1024 + nr] = __float2bfloat16(rg * hf[bm * 1024 + nr]);
                }
            }
        }
        grid_barrier(flags, go, g, ++gen);

        // ================= Phase 2: candidate + blend =================
        if (wave < 2) {
            const short* Ax = xt + (mb2 + r15) * 512 + kk;
            const short* As = (const short*)sb + (mb2 + r15) * 1024 + kk;
            f32x4 acc = {0.f, 0.f, 0.f, 0.f};
#pragma unroll 8
            for (int ki = 0; ki < 16; ++ki) {
                bf16x8 a = *(const bf16x8*)(Ax + ki * 32);
                bf16x8 w = *(const bf16x8*)(w2 + (r15 * 192 + ((ki * 4 + q) ^ sw)) * 8);
                acc = __builtin_amdgcn_mfma_f32_16x16x32_bf16(a, w, acc, 0, 0, 0);
            }
#pragma unroll 8
            for (int ki = 16; ki < 48; ++ki) {
                bf16x8 a = *(const bf16x8*)(As + (ki - 16) * 32);
                bf16x8 w = *(const bf16x8*)(w2 + (r15 * 192 + ((ki * 4 + q) ^ sw)) * 8);
                acc = __builtin_amdgcn_mfma_f32_16x16x32_bf16(a, w, acc, 0, 0, 0);
            }
            float* outt = out + (long long)t * 64 * 1024;
#pragma unroll
            for (int v = 0; v < 4; ++v) {
                int bm = mbase2 + v;
                float c = tanhf(acc[v] + bias2);
                float z = zf[bm * 1024 + nc2];
                float h_old = hf[bm * 1024 + nc2];
                float h_new = (1.0f - z) * h_old + z * c;
                outt[bm * 1024 + nc2] = h_new;
                hf[bm * 1024 + nc2] = h_new;
                hb[bm * 1024 + nc2] = __float2bfloat16(h_new);
            }
        }
        grid_barrier(flags, go, g, ++gen);
    }
}

extern "C" void kernel_launch(void* const* d_in, const int* in_sizes, int n_in,
                              void* d_out, int out_size, void* d_ws, size_t ws_size,
                              hipStream_t stream)
{
    (void)in_sizes; (void)n_in; (void)out_size; (void)ws_size;
    const float* x  = (const float*)d_in[0];
    const float* h0 = (const float*)d_in[1];
    const float* Wz = (const float*)d_in[2];
    const float* bz = (const float*)d_in[3];
    const float* Wr = (const float*)d_in[4];
    const float* br = (const float*)d_in[5];
    const float* Wc = (const float*)d_in[6];
    const float* bc = (const float*)d_in[7];
    float* out = (float*)d_out;

    // ws layout (bytes, 256-aligned): total ~43.8 MB
    char* ws = (char*)d_ws;
    __hip_bfloat16* Wzr = (__hip_bfloat16*)(ws);              // [2048][1536] bf16
    __hip_bfloat16* Wcb = (__hip_bfloat16*)(ws + 6291456);    // [1024][1536] bf16
    __hip_bfloat16* xb  = (__hip_bfloat16*)(ws + 9437184);    // [512][64][512] bf16
    float*          hf  = (float*)(ws + 42991616);            // [64][1024] f32
    __hip_bfloat16* hb  = (__hip_bfloat16*)(ws + 43253760);   // [64][1024] bf16
    __hip_bfloat16* sb  = (__hip_bfloat16*)(ws + 43384832);   // [64][1024] bf16
    float*          zf  = (float*)(ws + 43515904);            // [64][1024] f32
    unsigned int*  sync = (unsigned int*)(ws + 43778048);     // flags[128*16]+go

    k_convert_weights<<<1024, 256, 0, stream>>>(Wz, Wr, Wc, Wzr, Wcb);
    k_convert_x<<<2048, 256, 0, stream>>>(x, xb);
    k_init_h<<<256, 256, 0, stream>>>(h0, hf, hb);
    (void)hipMemsetAsync(sync, 0, (NWG * 16 + 16) * sizeof(unsigned int), stream);

    k_gru_persistent<<<NWG, 256, 0, stream>>>(
        xb, hf, hb, Wzr, Wcb, bz, br, bc, zf, sb, out, sync);
}